// Round 2
// baseline (5979.760 us; speedup 1.0000x reference)
//
#include <hip/hip_runtime.h>
#include <hip/hip_bf16.h>

#define TT 2048
#define BB 256
#define HH 64
#define OO 12

__device__ __forceinline__ float rl(float v, int k) {
  return __uint_as_float(__builtin_amdgcn_readlane(__float_as_uint(v), k));
}
__device__ __forceinline__ float sigf(float x)   { return 1.f / (1.f + __expf(-x)); }
__device__ __forceinline__ float tanhf2(float x) { return 2.f / (1.f + __expf(-2.f * x)) - 1.f; }
__device__ __forceinline__ float bflo(unsigned u) { return __uint_as_float(u << 16); }
__device__ __forceinline__ float bfhi(unsigned u) { return __uint_as_float(u & 0xffff0000u); }

// 32-MAC recurrent-h dot: h is in-lane (every wave holds full h), readlane broadcast.
template<int BASE>
__device__ __forceinline__ float hdot(float h, const float* wh) {
  float a0 = 0.f, a1 = 0.f, a2 = 0.f, a3 = 0.f;
#pragma unroll
  for (int j = 0; j < 32; j += 4) {
    a0 += rl(h, BASE + j + 0) * wh[j + 0];
    a1 += rl(h, BASE + j + 1) * wh[j + 1];
    a2 += rl(h, BASE + j + 2) * wh[j + 2];
    a3 += rl(h, BASE + j + 3) * wh[j + 3];
  }
  return (a0 + a1) + (a2 + a3);
}

// 32-MAC input dot against the wave-uniform x-row buffer.
__device__ __forceinline__ float xdot(const float4 (&xb)[8], const float* wx) {
  float a0 = 0.f, a1 = 0.f, a2 = 0.f, a3 = 0.f;
#pragma unroll
  for (int j = 0; j < 8; j++) {
    a0 += xb[j].x * wx[4 * j + 0];
    a1 += xb[j].y * wx[4 * j + 1];
    a2 += xb[j].z * wx[4 * j + 2];
    a3 += xb[j].w * wx[4 * j + 3];
  }
  return (a0 + a1) + (a2 + a3);
}

// One block per batch element. 512 threads = 8 waves.
// wave&3 = gate quarter (i,f,g~,o), wave>>2 = K-half. lane = hidden unit.
// Thread computes a 64-MAC partial gate (32 x-side + 32 h-side); halves are
// summed through LDS. All waves redundantly combine c,h so h stays in-lane.
template<int IN, bool L0, bool BF>
__global__ __launch_bounds__(512, 2)
void lstm_layer(const void* __restrict__ xin_v,
                void* __restrict__ hs_v,
                const float* __restrict__ Wih,
                const float* __restrict__ Whh,
                const float* __restrict__ bih,
                const float* __restrict__ bhh,
                const float* __restrict__ h0,
                const float* __restrict__ c0,
                float* __restrict__ hn,
                float* __restrict__ cn) {
  const int b    = blockIdx.x;
  const int tid  = threadIdx.x;
  const int lane = tid & 63;
  const int wave = tid >> 6;
  const int gate = wave & 3;
  const int half = wave >> 2;
  const int gout = gate * 64 + lane;          // output gate index [0,256)
  const int XOFF = half ? (IN - 32) : 0;      // x k-range: [0,IN-32) / [IN-32,IN)

  __shared__ float gbuf[2][512];

  // ---- resident weights: 64 floats/thread (no AGPR spill) ----
  float wx[32], wh[32];
#pragma unroll
  for (int j = 0; j < 32; j++) {
    const bool valid = half ? true : (j < IN - 32);
    wx[j] = valid ? Wih[(size_t)gout * IN + XOFF + j] : 0.f;
    wh[j] = Whh[(size_t)gout * HH + half * 32 + j];
  }
  const float bias = bih[gout] + bhh[gout];

  float h = h0[b * HH + lane];
  float c = c0[b * HH + lane];

  // ---- input-row pointers (wave-uniform addresses -> broadcast loads) ----
  const float*          xrow0 = (const float*)xin_v + (size_t)b * TT * IN + XOFF;      // L0
  const float*          xrowF = (const float*)xin_v + (size_t)b * HH + XOFF;           // fp32 hs
  const __hip_bfloat16* xrowB = (const __hip_bfloat16*)xin_v + (size_t)b * HH + XOFF;  // bf16 hs

  float*          hsf = (float*)hs_v + (size_t)b * HH + lane;
  __hip_bfloat16* hsb = (__hip_bfloat16*)hs_v + (size_t)b * HH + lane;

  auto loadrow = [&](int t, float4 (&dst)[8]) {
    if (t >= TT) return;
    if (L0) {
      const float4* r = reinterpret_cast<const float4*>(xrow0 + (size_t)t * IN);
#pragma unroll
      for (int j = 0; j < 8; j++) dst[j] = r[j];
    } else if (!BF) {
      const float4* r = reinterpret_cast<const float4*>(xrowF + (size_t)t * (BB * HH));
#pragma unroll
      for (int j = 0; j < 8; j++) dst[j] = r[j];
    } else {
      const uint4* r = reinterpret_cast<const uint4*>(xrowB + (size_t)t * (BB * HH));
#pragma unroll
      for (int j = 0; j < 4; j++) {
        uint4 q = r[j];
        dst[2 * j + 0] = make_float4(bflo(q.x), bfhi(q.x), bflo(q.y), bfhi(q.y));
        dst[2 * j + 1] = make_float4(bflo(q.z), bfhi(q.z), bflo(q.w), bfhi(q.w));
      }
    }
  };

  auto gpart = [&](const float4 (&cons)[8]) -> float {
    return half ? (xdot(cons, wx) + hdot<32>(h, wh))
                : (xdot(cons, wx) + hdot<0>(h, wh) + bias);
  };

  float4 bufA[8], bufB[8];
  loadrow(0, bufA);
  loadrow(1, bufB);

  // gates(0) from x(0), h0
  gbuf[0][half * 256 + gate * 64 + lane] = gpart(bufA);
  __syncthreads();

  // iteration t: gbuf[t&1] holds gates(t); cons holds x(t+1); refill <- x(t+2)
  auto step = [&](int t, const float4 (&cons)[8], float4 (&refill)[8]) {
    loadrow(t + 2, refill);  // prefetch (VMEM, lands next iteration)

    const float* gb = &gbuf[t & 1][0];
    float p0 = gb[lane]       + gb[256 + lane];
    float p1 = gb[64 + lane]  + gb[320 + lane];
    float p2 = gb[128 + lane] + gb[384 + lane];
    float p3 = gb[192 + lane] + gb[448 + lane];

    c = sigf(p1) * c + sigf(p0) * tanhf2(p2);
    h = sigf(p3) * tanhf2(c);

    if (tid < 64) {
      if (BF) hsb[(size_t)t * (BB * HH)] = __float2bfloat16(h);
      else    hsf[(size_t)t * (BB * HH)] = h;
    }

    if (t + 1 < TT)
      gbuf[(t + 1) & 1][half * 256 + gate * 64 + lane] = gpart(cons);

    __syncthreads();
  };

  for (int t = 0; t < TT; t += 2) {
    step(t,     bufB, bufA);
    step(t + 1, bufA, bufB);
  }

  if (tid < 64) {
    hn[b * HH + lane] = h;
    cn[b * HH + lane] = c;
  }
}

// y[b,t,:] = W_out @ hs[t,b,:] + b_out. One thread per (t,b) row.
template<bool BF>
__global__ __launch_bounds__(256, 1)
void out_proj(const void* __restrict__ hs_v,
              const float* __restrict__ Wout,
              const float* __restrict__ bout,
              float* __restrict__ y) {
  const int g = blockIdx.x * 256 + threadIdx.x;  // g = t*256 + b
  const int t = g >> 8;
  const int b = g & 255;

  float hrow[HH];
  if (BF) {
    const __hip_bfloat16* r = (const __hip_bfloat16*)hs_v + (size_t)g * HH;
#pragma unroll
    for (int k = 0; k < HH; k++) hrow[k] = __bfloat162float(r[k]);
  } else {
    const float* r = (const float*)hs_v + (size_t)g * HH;
#pragma unroll
    for (int k = 0; k < HH; k++) hrow[k] = r[k];
  }

  float* yp = y + (size_t)b * TT * OO + (size_t)t * OO;
#pragma unroll
  for (int o = 0; o < OO; o++) {
    float a0 = bout[o], a1 = 0.f, a2 = 0.f, a3 = 0.f;
#pragma unroll
    for (int k = 0; k < HH; k += 4) {
      a0 += hrow[k + 0] * Wout[o * HH + k + 0];
      a1 += hrow[k + 1] * Wout[o * HH + k + 1];
      a2 += hrow[k + 2] * Wout[o * HH + k + 2];
      a3 += hrow[k + 3] * Wout[o * HH + k + 3];
    }
    yp[o] = (a0 + a1) + (a2 + a3);
  }
}

extern "C" void kernel_launch(void* const* d_in, const int* in_sizes, int n_in,
                              void* d_out, int out_size, void* d_ws, size_t ws_size,
                              hipStream_t stream) {
  const float* x    = (const float*)d_in[0];
  const float* h0   = (const float*)d_in[1];
  const float* c0   = (const float*)d_in[2];
  const float* Wih0 = (const float*)d_in[3];
  const float* Whh0 = (const float*)d_in[4];
  const float* bih0 = (const float*)d_in[5];
  const float* bhh0 = (const float*)d_in[6];
  const float* Wih1 = (const float*)d_in[7];
  const float* Whh1 = (const float*)d_in[8];
  const float* bih1 = (const float*)d_in[9];
  const float* bhh1 = (const float*)d_in[10];
  const float* Wih2 = (const float*)d_in[11];
  const float* Whh2 = (const float*)d_in[12];
  const float* bih2 = (const float*)d_in[13];
  const float* bhh2 = (const float*)d_in[14];
  const float* Wout = (const float*)d_in[15];
  const float* bout = (const float*)d_in[16];

  float* y  = (float*)d_out;
  float* hn = y + (size_t)BB * TT * OO;
  float* cn = hn + (size_t)3 * BB * HH;

  const size_t needF = (size_t)TT * BB * HH * sizeof(float);
  const bool   bf    = ws_size < needF;  // bf16 hs fallback if scratch is tight
  void* hs = d_ws;

  dim3 grid(BB), blk(512);
  dim3 ygrid(TT * BB / 256), yblk(256);

  if (!bf) {
    lstm_layer<60, true,  false><<<grid, blk, 0, stream>>>(x,  hs, Wih0, Whh0, bih0, bhh0,
        h0 + 0 * BB * HH, c0 + 0 * BB * HH, hn + 0 * BB * HH, cn + 0 * BB * HH);
    lstm_layer<64, false, false><<<grid, blk, 0, stream>>>(hs, hs, Wih1, Whh1, bih1, bhh1,
        h0 + 1 * BB * HH, c0 + 1 * BB * HH, hn + 1 * BB * HH, cn + 1 * BB * HH);
    lstm_layer<64, false, false><<<grid, blk, 0, stream>>>(hs, hs, Wih2, Whh2, bih2, bhh2,
        h0 + 2 * BB * HH, c0 + 2 * BB * HH, hn + 2 * BB * HH, cn + 2 * BB * HH);
    out_proj<false><<<ygrid, yblk, 0, stream>>>(hs, Wout, bout, y);
  } else {
    lstm_layer<60, true,  true><<<grid, blk, 0, stream>>>(x,  hs, Wih0, Whh0, bih0, bhh0,
        h0 + 0 * BB * HH, c0 + 0 * BB * HH, hn + 0 * BB * HH, cn + 0 * BB * HH);
    lstm_layer<64, false, true><<<grid, blk, 0, stream>>>(hs, hs, Wih1, Whh1, bih1, bhh1,
        h0 + 1 * BB * HH, c0 + 1 * BB * HH, hn + 1 * BB * HH, cn + 1 * BB * HH);
    lstm_layer<64, false, true><<<grid, blk, 0, stream>>>(hs, hs, Wih2, Whh2, bih2, bhh2,
        h0 + 2 * BB * HH, c0 + 2 * BB * HH, hn + 2 * BB * HH, cn + 2 * BB * HH);
    out_proj<true><<<ygrid, yblk, 0, stream>>>(hs, Wout, bout, y);
  }
}

// Round 3
// 3032.263 us; speedup vs baseline: 1.9720x; 1.9720x over previous
//
#include <hip/hip_runtime.h>
#include <hip/hip_fp16.h>

#define TT 2048
#define BB 256
#define HH 64
#define II 60
#define OO 12
#define LL 3

typedef _Float16 h2 __attribute__((ext_vector_type(2)));

#ifndef __has_builtin
#define __has_builtin(x) 0
#endif
#if __has_builtin(__builtin_amdgcn_fdot2)
#define FDOT2(a, b, c) __builtin_amdgcn_fdot2((a), (b), (c), false)
#else
#define FDOT2(a, b, c) ((c) + (float)(a)[0] * (float)(b)[0] + (float)(a)[1] * (float)(b)[1])
#endif

__device__ __forceinline__ h2 bc(unsigned u) { return __builtin_bit_cast(h2, u); }
__device__ __forceinline__ float sigf(float x)   { return 1.f / (1.f + __expf(-x)); }
__device__ __forceinline__ float tanhf2(float x) { return 2.f / (1.f + __expf(-2.f * x)) - 1.f; }

// ---- pre-pass: x [B,T,60] fp32 -> xh [B,T,64] f16 (zero-padded) ----
__global__ __launch_bounds__(256)
void xcvt(const float* __restrict__ x, unsigned* __restrict__ xh) {
  long v = (long)blockIdx.x * 256 + threadIdx.x;   // index over half2 units (B*T*32)
  int  c2 = (int)(v & 31);
  long row = v >> 5;
  int k0 = 2 * c2, k1 = k0 + 1;
  const float* xr = x + row * II;
  float f0 = (k0 < II) ? xr[k0] : 0.f;
  float f1 = (k1 < II) ? xr[k1] : 0.f;
  h2 p; p[0] = (_Float16)f0; p[1] = (_Float16)f1;
  xh[v] = __builtin_bit_cast(unsigned, p);
}

// ---- fused 3-layer wavefront LSTM ----
// Block b = batch b. 768 threads = 3 teams x 256 (team l = layer l, 4 waves).
// Thread: gate g = tid&255, unit u = g&63. Phase s: team l combines t=s-l,
// then (after barrier) computes gates(t+1) with v_dot2_f32_f16 against f16
// rows handed off via LDS (uniform-address ds_read_b128 = broadcast).
__global__ __launch_bounds__(768, 3)
void lstm3_fused(const unsigned* __restrict__ xh,
                 _Float16* __restrict__ hs,
                 const float* __restrict__ Wih0, const float* __restrict__ Whh0,
                 const float* __restrict__ bih0, const float* __restrict__ bhh0,
                 const float* __restrict__ Wih1, const float* __restrict__ Whh1,
                 const float* __restrict__ bih1, const float* __restrict__ bhh1,
                 const float* __restrict__ Wih2, const float* __restrict__ Whh2,
                 const float* __restrict__ bih2, const float* __restrict__ bhh2,
                 const float* __restrict__ h0, const float* __restrict__ c0,
                 float* __restrict__ hn, float* __restrict__ cn) {
  const int b   = blockIdx.x;
  const int tid = threadIdx.x;
  const int l   = tid >> 8;
  const int g   = tid & 255;
  const int u   = g & 63;

  __shared__ float gbuf[LL][2][256];
  __shared__ __align__(16) _Float16 hbf[LL][4][HH];

  const float* Wih = (l == 0) ? Wih0 : (l == 1) ? Wih1 : Wih2;
  const float* Whh = (l == 0) ? Whh0 : (l == 1) ? Whh1 : Whh2;
  const float* bih = (l == 0) ? bih0 : (l == 1) ? bih1 : bih2;
  const float* bhh = (l == 0) ? bhh0 : (l == 1) ? bhh1 : bhh2;
  const int IN = (l == 0) ? II : HH;

  // resident weights: w[0..31] = x-side, w[32..63] = recurrent, packed f16x2
  h2 w[64];
#pragma unroll
  for (int j = 0; j < 32; j++) {
    int k0 = 2 * j, k1 = k0 + 1;
    float f0 = (k0 < IN) ? Wih[g * IN + k0] : 0.f;
    float f1 = (k1 < IN) ? Wih[g * IN + k1] : 0.f;
    h2 p; p[0] = (_Float16)f0; p[1] = (_Float16)f1;
    w[j] = p;
    h2 q; q[0] = (_Float16)Whh[g * HH + k0]; q[1] = (_Float16)Whh[g * HH + k1];
    w[32 + j] = q;
  }
  const float bias = bih[g] + bhh[g];

  float hreg = h0[(l * BB + b) * HH + u];
  float creg = c0[(l * BB + b) * HH + u];

  uint4 nxt4[8];

  // ---- prologue: publish h0 rows (slot (l-1)&3), team 0 computes gates(0) ----
  if (g < 64) hbf[l][(l + 3) & 3][u] = (_Float16)hreg;
  __syncthreads();
  if (l == 0) {
    const uint4* xr = (const uint4*)(xh + (long)b * TT * 32);
    float acc = bias;
#pragma unroll
    for (int jj = 0; jj < 8; jj++) {
      uint4 q = xr[jj];
      acc = FDOT2(bc(q.x), w[4 * jj + 0], acc);
      acc = FDOT2(bc(q.y), w[4 * jj + 1], acc);
      acc = FDOT2(bc(q.z), w[4 * jj + 2], acc);
      acc = FDOT2(bc(q.w), w[4 * jj + 3], acc);
    }
    const uint4* hr = (const uint4*)&hbf[0][3][0];
#pragma unroll
    for (int jj = 0; jj < 8; jj++) {
      uint4 q = hr[jj];
      acc = FDOT2(bc(q.x), w[32 + 4 * jj + 0], acc);
      acc = FDOT2(bc(q.y), w[32 + 4 * jj + 1], acc);
      acc = FDOT2(bc(q.z), w[32 + 4 * jj + 2], acc);
      acc = FDOT2(bc(q.w), w[32 + 4 * jj + 3], acc);
    }
    gbuf[0][0][g] = acc;
    const uint4* xr1 = (const uint4*)(xh + ((long)b * TT + 1) * 32);
#pragma unroll
    for (int jj = 0; jj < 8; jj++) nxt4[jj] = xr1[jj];
  }
  __syncthreads();

  // ---- main loop: phases s = 0 .. T+1 ----
  for (int s = 0; s < TT + 2; s++) {
    const int t    = s - l;
    const int slot = s & 3;
    const int par  = s & 1;

    if (t >= 0 && t < TT) {
      float gi = gbuf[l][par][u];
      float gf = gbuf[l][par][u + 64];
      float gg = gbuf[l][par][u + 128];
      float go = gbuf[l][par][u + 192];
      creg = sigf(gf) * creg + sigf(gi) * tanhf2(gg);
      hreg = sigf(go) * tanhf2(creg);
      if (g < 64) {
        hbf[l][slot][u] = (_Float16)hreg;
        if (l == 2) hs[((long)b * TT + t) * HH + u] = (_Float16)hreg;
      }
    }
    __syncthreads();  // hbf rows for this phase are ready

    const int tn = t + 1;
    if (tn >= 0 && tn < TT) {
      float acc = bias;
      if (l == 0) {
#pragma unroll
        for (int jj = 0; jj < 8; jj++) {
          uint4 q = nxt4[jj];
          acc = FDOT2(bc(q.x), w[4 * jj + 0], acc);
          acc = FDOT2(bc(q.y), w[4 * jj + 1], acc);
          acc = FDOT2(bc(q.z), w[4 * jj + 2], acc);
          acc = FDOT2(bc(q.w), w[4 * jj + 3], acc);
        }
        if (s + 2 < TT) {
          const uint4* xr = (const uint4*)(xh + ((long)b * TT + (s + 2)) * 32);
#pragma unroll
          for (int jj = 0; jj < 8; jj++) nxt4[jj] = xr[jj];
        }
      } else {
        const uint4* xr4 = (const uint4*)&hbf[l - 1][slot][0];
#pragma unroll
        for (int jj = 0; jj < 8; jj++) {
          uint4 q = xr4[jj];
          acc = FDOT2(bc(q.x), w[4 * jj + 0], acc);
          acc = FDOT2(bc(q.y), w[4 * jj + 1], acc);
          acc = FDOT2(bc(q.z), w[4 * jj + 2], acc);
          acc = FDOT2(bc(q.w), w[4 * jj + 3], acc);
        }
      }
      const uint4* hr4 = (const uint4*)&hbf[l][slot][0];
#pragma unroll
      for (int jj = 0; jj < 8; jj++) {
        uint4 q = hr4[jj];
        acc = FDOT2(bc(q.x), w[32 + 4 * jj + 0], acc);
        acc = FDOT2(bc(q.y), w[32 + 4 * jj + 1], acc);
        acc = FDOT2(bc(q.z), w[32 + 4 * jj + 2], acc);
        acc = FDOT2(bc(q.w), w[32 + 4 * jj + 3], acc);
      }
      gbuf[l][par ^ 1][g] = acc;
    }
    __syncthreads();  // gbuf(t+1) ready; hbf slot safe to reuse
  }

  if (g < 64) {
    hn[(l * BB + b) * HH + u] = hreg;
    cn[(l * BB + b) * HH + u] = creg;
  }
}

// ---- output projection: y[b,t,:] = W_out @ h2row + b_out ----
__global__ __launch_bounds__(256)
void oproj(const _Float16* __restrict__ hs,
           const float* __restrict__ Wout,
           const float* __restrict__ bout,
           float* __restrict__ y) {
  __shared__ float Wo[OO * HH];
  __shared__ float bo[OO];
  const int tid = threadIdx.x;
  for (int i = tid; i < OO * HH; i += 256) Wo[i] = Wout[i];
  if (tid < OO) bo[tid] = bout[tid];
  __syncthreads();

  const long r = (long)blockIdx.x * 256 + tid;  // r = b*T + t
  const uint4* h4 = (const uint4*)(hs + r * HH);
  float hf[HH];
#pragma unroll
  for (int jj = 0; jj < 8; jj++) {
    uint4 q = h4[jj];
    h2 p0 = bc(q.x), p1 = bc(q.y), p2 = bc(q.z), p3 = bc(q.w);
    hf[8 * jj + 0] = (float)p0[0]; hf[8 * jj + 1] = (float)p0[1];
    hf[8 * jj + 2] = (float)p1[0]; hf[8 * jj + 3] = (float)p1[1];
    hf[8 * jj + 4] = (float)p2[0]; hf[8 * jj + 5] = (float)p2[1];
    hf[8 * jj + 6] = (float)p3[0]; hf[8 * jj + 7] = (float)p3[1];
  }

  float out[OO];
#pragma unroll
  for (int o = 0; o < OO; o++) {
    float a0 = bo[o], a1 = 0.f, a2 = 0.f, a3 = 0.f;
#pragma unroll
    for (int k = 0; k < HH; k += 4) {
      a0 += hf[k + 0] * Wo[o * HH + k + 0];
      a1 += hf[k + 1] * Wo[o * HH + k + 1];
      a2 += hf[k + 2] * Wo[o * HH + k + 2];
      a3 += hf[k + 3] * Wo[o * HH + k + 3];
    }
    out[o] = (a0 + a1) + (a2 + a3);
  }
  float4* yp = (float4*)(y + r * OO);
#pragma unroll
  for (int q = 0; q < 3; q++)
    yp[q] = make_float4(out[4 * q], out[4 * q + 1], out[4 * q + 2], out[4 * q + 3]);
}

extern "C" void kernel_launch(void* const* d_in, const int* in_sizes, int n_in,
                              void* d_out, int out_size, void* d_ws, size_t ws_size,
                              hipStream_t stream) {
  const float* x    = (const float*)d_in[0];
  const float* h0   = (const float*)d_in[1];
  const float* c0   = (const float*)d_in[2];
  const float* Wih0 = (const float*)d_in[3];
  const float* Whh0 = (const float*)d_in[4];
  const float* bih0 = (const float*)d_in[5];
  const float* bhh0 = (const float*)d_in[6];
  const float* Wih1 = (const float*)d_in[7];
  const float* Whh1 = (const float*)d_in[8];
  const float* bih1 = (const float*)d_in[9];
  const float* bhh1 = (const float*)d_in[10];
  const float* Wih2 = (const float*)d_in[11];
  const float* Whh2 = (const float*)d_in[12];
  const float* bih2 = (const float*)d_in[13];
  const float* bhh2 = (const float*)d_in[14];
  const float* Wout = (const float*)d_in[15];
  const float* bout = (const float*)d_in[16];

  float* y  = (float*)d_out;
  float* hn = y + (size_t)BB * TT * OO;
  float* cn = hn + (size_t)LL * BB * HH;

  // ws: [0, 64MiB) = xh (f16 padded x rows), [64MiB, 128MiB) = hs (f16 layer-2 h)
  unsigned*  xh = (unsigned*)d_ws;
  _Float16*  hs = (_Float16*)((char*)d_ws + (size_t)BB * TT * HH * sizeof(_Float16));

  xcvt<<<dim3(BB * TT * 32 / 256), dim3(256), 0, stream>>>(x, xh);
  lstm3_fused<<<dim3(BB), dim3(768), 0, stream>>>(xh, hs,
      Wih0, Whh0, bih0, bhh0, Wih1, Whh1, bih1, bhh1, Wih2, Whh2, bih2, bhh2,
      h0, c0, hn, cn);
  oproj<<<dim3(BB * TT / 256), dim3(256), 0, stream>>>(hs, Wout, bout, y);
}

// Round 4
// 2003.663 us; speedup vs baseline: 2.9844x; 1.5134x over previous
//
#include <hip/hip_runtime.h>
#include <hip/hip_fp16.h>

#define TT 2048
#define BB 256
#define HH 64
#define II 60
#define OO 12
#define LL 3

typedef _Float16 h2 __attribute__((ext_vector_type(2)));
typedef unsigned u32x4 __attribute__((ext_vector_type(4)));

#ifndef __has_builtin
#define __has_builtin(x) 0
#endif

#if __has_builtin(__builtin_amdgcn_fdot2)
__device__ __forceinline__ float dot2(unsigned a, unsigned b, float acc) {
  return __builtin_amdgcn_fdot2(__builtin_bit_cast(h2, a), __builtin_bit_cast(h2, b), acc, false);
}
#else
// clang fuses cvt_f32_f16 + fma into v_fma_mix_f32 on CDNA
__device__ __forceinline__ float dot2(unsigned a, unsigned b, float acc) {
  h2 A = __builtin_bit_cast(h2, a), B = __builtin_bit_cast(h2, b);
  acc = fmaf((float)A[0], (float)B[0], acc);
  acc = fmaf((float)A[1], (float)B[1], acc);
  return acc;
}
#endif

__device__ __forceinline__ float sigf(float x)   { return 1.f / (1.f + __expf(-x)); }
__device__ __forceinline__ float tanhf2(float x) { return 2.f / (1.f + __expf(-2.f * x)) - 1.f; }

// 64-MAC dot against a register row (8 x u32x4 = 64 f16), 4 chains.
__device__ __forceinline__ float dotreg(const u32x4 (&P)[8], const unsigned* w, float acc) {
  float a0 = acc, a1 = 0.f, a2 = 0.f, a3 = 0.f;
#pragma unroll
  for (int j = 0; j < 8; j++) {
    a0 = dot2(P[j][0], w[4 * j + 0], a0);
    a1 = dot2(P[j][1], w[4 * j + 1], a1);
    a2 = dot2(P[j][2], w[4 * j + 2], a2);
    a3 = dot2(P[j][3], w[4 * j + 3], a3);
  }
  return (a0 + a1) + (a2 + a3);
}

// 64-MAC dot against an LDS f16 row (uniform address -> broadcast reads).
__device__ __forceinline__ float dotlds(const _Float16* row, const unsigned* w, float acc) {
  const unsigned* rp = (const unsigned*)row;
  float a0 = acc, a1 = 0.f, a2 = 0.f, a3 = 0.f;
#pragma unroll
  for (int j = 0; j < 32; j += 4) {
    a0 = dot2(rp[j + 0], w[j + 0], a0);
    a1 = dot2(rp[j + 1], w[j + 1], a1);
    a2 = dot2(rp[j + 2], w[j + 2], a2);
    a3 = dot2(rp[j + 3], w[j + 3], a3);
  }
  return (a0 + a1) + (a2 + a3);
}

// ---- pre-pass: x [B,T,60] fp32 -> xh [B,T,64] f16 (zero-padded) ----
__global__ __launch_bounds__(256)
void xcvt(const float* __restrict__ x, unsigned* __restrict__ xh) {
  long v = (long)blockIdx.x * 256 + threadIdx.x;   // half2 units (B*T*32)
  int  c2 = (int)(v & 31);
  long row = v >> 5;
  int k0 = 2 * c2, k1 = k0 + 1;
  const float* xr = x + row * II;
  float f0 = (k0 < II) ? xr[k0] : 0.f;
  float f1 = (k1 < II) ? xr[k1] : 0.f;
  h2 p; p[0] = (_Float16)f0; p[1] = (_Float16)f1;
  xh[v] = __builtin_bit_cast(unsigned, p);
}

// ---- fused 3-layer wavefront LSTM ----
// Block b = batch b. 768 threads = 3 teams x 256 (team l = layer l).
// Thread owns gate g = tid&255 (wave-in-team = gate type). Per phase s,
// team l: (A) wave l combines t=s-l from gbuf, publishes h to hbf;
// (B) all 4 waves compute gates(t+1) = bias + [x|h].W via dot2/fma_mix
// against VGPR-pinned f16 weights, write gbuf. Two barriers per phase.
__global__ __launch_bounds__(768, 3)
void lstm3_fused(const unsigned* __restrict__ xh,
                 _Float16* __restrict__ hs,
                 const float* __restrict__ Wih0, const float* __restrict__ Whh0,
                 const float* __restrict__ bih0, const float* __restrict__ bhh0,
                 const float* __restrict__ Wih1, const float* __restrict__ Whh1,
                 const float* __restrict__ bih1, const float* __restrict__ bhh1,
                 const float* __restrict__ Wih2, const float* __restrict__ Whh2,
                 const float* __restrict__ bih2, const float* __restrict__ bhh2,
                 const float* __restrict__ h0, const float* __restrict__ c0,
                 float* __restrict__ hn, float* __restrict__ cn) {
  const int b   = blockIdx.x;
  const int tid = threadIdx.x;
  const int l   = tid >> 8;
  const int g   = tid & 255;
  const int u   = g & 63;
  const int w   = g >> 6;          // wave-in-team = gate type
  const bool cw = (w == l);        // combine wave (spreads to SIMD 0,1,2)

  __shared__ float gbuf[LL][2][256];
  __shared__ __align__(16) _Float16 hbf[LL][4][HH];

  const float* Wih = (l == 0) ? Wih0 : (l == 1) ? Wih1 : Wih2;
  const float* Whh = (l == 0) ? Whh0 : (l == 1) ? Whh1 : Whh2;
  const float* bih = (l == 0) ? bih0 : (l == 1) ? bih1 : bih2;
  const float* bhh = (l == 0) ? bhh0 : (l == 1) ? bhh1 : bhh2;
  const int IN = (l == 0) ? II : HH;

  // resident weights: 64 uints (h2 pairs), pinned to arch VGPRs
  unsigned wx[32], wh[32];
#pragma unroll
  for (int j = 0; j < 32; j++) {
    int k0 = 2 * j, k1 = k0 + 1;
    float f0 = (k0 < IN) ? Wih[(size_t)g * IN + k0] : 0.f;
    float f1 = (k1 < IN) ? Wih[(size_t)g * IN + k1] : 0.f;
    h2 p; p[0] = (_Float16)f0; p[1] = (_Float16)f1;
    wx[j] = __builtin_bit_cast(unsigned, p);
    h2 q; q[0] = (_Float16)Whh[(size_t)g * HH + k0]; q[1] = (_Float16)Whh[(size_t)g * HH + k1];
    wh[j] = __builtin_bit_cast(unsigned, q);
  }
#pragma unroll
  for (int j = 0; j < 32; j++) {
    asm volatile("" : "+v"(wx[j]));
    asm volatile("" : "+v"(wh[j]));
  }
  const float bias = bih[g] + bhh[g];

  float hreg = h0[(l * BB + b) * HH + u];
  float creg = c0[(l * BB + b) * HH + u];

  const unsigned* xbase = xh + (long)b * TT * 32;

  // ---- prologue ----
  if (cw) hbf[l][(l + 3) & 3][u] = (_Float16)hreg;   // seed h_l(init) in slot (l-1)&3
  __syncthreads();

  u32x4 PA[8], PB[8];
  if (l == 0) {
    u32x4 T0[8];
    const u32x4* xr0 = (const u32x4*)(xbase + 0 * 32);
    const u32x4* xr1 = (const u32x4*)(xbase + 1 * 32);
    const u32x4* xr2 = (const u32x4*)(xbase + 2 * 32);
#pragma unroll
    for (int j = 0; j < 8; j++) { T0[j] = xr0[j]; PA[j] = xr1[j]; PB[j] = xr2[j]; }
    float acc = dotreg(T0, wx, bias);
    acc = dotlds(&hbf[0][3][0], wh, acc);
    gbuf[0][0][g] = acc;                              // gates_0(0)
  }
  __syncthreads();

  // ---- phase body ----
  auto phase = [&](int s, u32x4 (&cur)[8]) {
    const int t    = s - l;
    const int slot = s & 3;

    // Stage A: combine (one wave per team)
    if (cw && t >= 0 && t < TT) {
      const float* gb = &gbuf[l][s & 1][0];
      float g0 = gb[u], g1 = gb[64 + u], g2 = gb[128 + u], g3 = gb[192 + u];
      creg = sigf(g1) * creg + sigf(g0) * tanhf2(g2);
      hreg = sigf(g3) * tanhf2(creg);
      hbf[l][slot][u] = (_Float16)hreg;
      if (l == 2) hs[((long)b * TT + t) * HH + u] = (_Float16)hreg;
      if (t == TT - 1) {
        hn[(l * BB + b) * HH + u] = hreg;
        cn[(l * BB + b) * HH + u] = creg;
      }
    }
    __syncthreads();   // hbf rows for this phase ready

    // Stage B: gates(t+1)
    const int tn = t + 1;
    if (tn >= 0 && tn < TT) {
      float acc;
      if (l == 0) acc = dotreg(cur, wx, bias);
      else        acc = dotlds(&hbf[l - 1][slot][0], wx, bias);
      acc = dotlds(&hbf[l][slot][0], wh, acc);
      gbuf[l][(s + 1) & 1][g] = acc;
      if (l == 0 && s + 3 < TT) {                     // refill: consumed at phase s+2
        const u32x4* xr = (const u32x4*)(xbase + (long)(s + 3) * 32);
#pragma unroll
        for (int j = 0; j < 8; j++) cur[j] = xr[j];
      }
    }
    __syncthreads();   // gbuf(t+1) ready
  };

  for (int s = 0; s < TT + 2; s += 2) {
    phase(s,     PA);
    phase(s + 1, PB);
  }
}

// ---- output projection: y[b,t,:] = W_out @ h_row + b_out ----
__global__ __launch_bounds__(256)
void oproj(const _Float16* __restrict__ hs,
           const float* __restrict__ Wout,
           const float* __restrict__ bout,
           float* __restrict__ y) {
  __shared__ float Wo[OO * HH];
  __shared__ float bo[OO];
  const int tid = threadIdx.x;
  for (int i = tid; i < OO * HH; i += 256) Wo[i] = Wout[i];
  if (tid < OO) bo[tid] = bout[tid];
  __syncthreads();

  const long r = (long)blockIdx.x * 256 + tid;  // r = b*T + t
  const uint4* h4 = (const uint4*)(hs + r * HH);
  float hf[HH];
#pragma unroll
  for (int jj = 0; jj < 8; jj++) {
    uint4 q = h4[jj];
    h2 p0 = __builtin_bit_cast(h2, q.x), p1 = __builtin_bit_cast(h2, q.y);
    h2 p2 = __builtin_bit_cast(h2, q.z), p3 = __builtin_bit_cast(h2, q.w);
    hf[8 * jj + 0] = (float)p0[0]; hf[8 * jj + 1] = (float)p0[1];
    hf[8 * jj + 2] = (float)p1[0]; hf[8 * jj + 3] = (float)p1[1];
    hf[8 * jj + 4] = (float)p2[0]; hf[8 * jj + 5] = (float)p2[1];
    hf[8 * jj + 6] = (float)p3[0]; hf[8 * jj + 7] = (float)p3[1];
  }

  float out[OO];
#pragma unroll
  for (int o = 0; o < OO; o++) {
    float a0 = bo[o], a1 = 0.f, a2 = 0.f, a3 = 0.f;
#pragma unroll
    for (int k = 0; k < HH; k += 4) {
      a0 += hf[k + 0] * Wo[o * HH + k + 0];
      a1 += hf[k + 1] * Wo[o * HH + k + 1];
      a2 += hf[k + 2] * Wo[o * HH + k + 2];
      a3 += hf[k + 3] * Wo[o * HH + k + 3];
    }
    out[o] = (a0 + a1) + (a2 + a3);
  }
  float4* yp = (float4*)(y + r * OO);
#pragma unroll
  for (int q = 0; q < 3; q++)
    yp[q] = make_float4(out[4 * q], out[4 * q + 1], out[4 * q + 2], out[4 * q + 3]);
}

extern "C" void kernel_launch(void* const* d_in, const int* in_sizes, int n_in,
                              void* d_out, int out_size, void* d_ws, size_t ws_size,
                              hipStream_t stream) {
  const float* x    = (const float*)d_in[0];
  const float* h0   = (const float*)d_in[1];
  const float* c0   = (const float*)d_in[2];
  const float* Wih0 = (const float*)d_in[3];
  const float* Whh0 = (const float*)d_in[4];
  const float* bih0 = (const float*)d_in[5];
  const float* bhh0 = (const float*)d_in[6];
  const float* Wih1 = (const float*)d_in[7];
  const float* Whh1 = (const float*)d_in[8];
  const float* bih1 = (const float*)d_in[9];
  const float* bhh1 = (const float*)d_in[10];
  const float* Wih2 = (const float*)d_in[11];
  const float* Whh2 = (const float*)d_in[12];
  const float* bih2 = (const float*)d_in[13];
  const float* bhh2 = (const float*)d_in[14];
  const float* Wout = (const float*)d_in[15];
  const float* bout = (const float*)d_in[16];

  float* y  = (float*)d_out;
  float* hn = y + (size_t)BB * TT * OO;
  float* cn = hn + (size_t)LL * BB * HH;

  // ws: [0, 32MiB) = xh (f16 padded x rows), then hs (f16 layer-2 h)
  unsigned*  xh = (unsigned*)d_ws;
  _Float16*  hs = (_Float16*)((char*)d_ws + (size_t)BB * TT * HH * sizeof(_Float16));

  xcvt<<<dim3(BB * TT * 32 / 256), dim3(256), 0, stream>>>(x, xh);
  lstm3_fused<<<dim3(BB), dim3(768), 0, stream>>>(xh, hs,
      Wih0, Whh0, bih0, bhh0, Wih1, Whh1, bih1, bhh1, Wih2, Whh2, bih2, bhh2,
      h0, c0, hn, cn);
  oproj<<<dim3(BB * TT / 256), dim3(256), 0, stream>>>(hs, Wout, bout, y);
}